// Round 3
// baseline (3495.841 us; speedup 1.0000x reference)
//
#include <hip/hip_runtime.h>
#include <cstdint>
#include <cstddef>

#define B_   2
#define N_   8192
#define M_   2048
#define K_   32
#define C0_  64
#define C1_  128
#define C2_  256
#define CIN_ 67

// Exact-match distance: reference computes sum((a-b)**2, axis=-1) in f32 as
// ((dx^2 + dy^2) + dz^2) with no FMA contraction. _rn intrinsics forbid
// contract-fast fma fusion (would flip argmax / radius-boundary decisions).
__device__ __forceinline__ float sqdist_rn(float ax, float ay, float az,
                                           float bx, float by, float bz) {
  float dx = __fsub_rn(ax, bx);
  float dy = __fsub_rn(ay, by);
  float dz = __fsub_rn(az, bz);
  return __fadd_rn(__fadd_rn(__fmul_rn(dx, dx), __fmul_rn(dy, dy)),
                   __fmul_rn(dz, dz));
}

__device__ __forceinline__ int morton8(int ix, int iy, int iz) {
  int m = 0;
#pragma unroll
  for (int b = 0; b < 3; ++b) {
    m |= (((ix >> b) & 1) << (3 * b + 2)) | (((iy >> b) & 1) << (3 * b + 1)) |
         (((iz >> b) & 1) << (3 * b + 0));
  }
  return m;
}

// u64 max across the wave via paired DPP (row_shr 1/2/4/8, row_bcast 15/31);
// cumulative max lands in lane 63. bound_ctrl=false + old=self => lanes with
// no source contribute their own value (max(v,v)=v). Exact tie-break is baked
// into the key (d | inv_pid | pos), so a plain unsigned max is sufficient.
__device__ __forceinline__ unsigned long long wave_max_u64_dpp(unsigned long long k) {
#define FPS_STEP(ctrl)                                                         \
  {                                                                            \
    int klo = (int)(unsigned)k, khi = (int)(unsigned)(k >> 32);                \
    int olo = __builtin_amdgcn_update_dpp(klo, klo, ctrl, 0xf, 0xf, false);    \
    int ohi = __builtin_amdgcn_update_dpp(khi, khi, ctrl, 0xf, 0xf, false);    \
    unsigned long long ok =                                                    \
        ((unsigned long long)(unsigned)ohi << 32) | (unsigned)olo;             \
    if (ok > k) k = ok;                                                        \
  }
  FPS_STEP(0x111)  // row_shr:1
  FPS_STEP(0x112)  // row_shr:2
  FPS_STEP(0x114)  // row_shr:4
  FPS_STEP(0x118)  // row_shr:8
  FPS_STEP(0x142)  // row_bcast:15
  FPS_STEP(0x143)  // row_bcast:31
#undef FPS_STEP
  return k;
}

// ---------------------------------------------------------------------------
// 1) Furthest point sampling — 4-wave block (256 thr, 1 wave/SIMD), LDS point
//    state, 2-level (thread-sphere -> bucket-sphere) pruning, ONE barrier per
//    iteration, NO atomics.
//
//    Round-2 post-mortem: 16-wave version was bound by per-iteration fixed
//    serialization scaling with wave count (16x winner-read chains + 16-deep
//    ds_max_u64 same-address RMW + waitcnt + wide barrier ~ 2800 cy/iter);
//    VALU work removal (0.44->0.39 busy) didn't move time. This version
//    shrinks the machine: 4 candidate slots, plain b64 writes, parity double
//    buffer (write s_cand[p^1][w] between barrier(it),barrier(it+1); reads of
//    s_cand[p^1] happen after barrier(it+1); next write after barrier(it+2):
//    every conflicting pair separated by a barrier -> race-free, no clears).
//
//    Thread t owns buckets 4t..4t+3 (8 morton-sorted pts each). Per-iter:
//    read 4 slots (16-way bcast) -> 2-step quad-DPP max -> winPos -> bcast
//    coord read -> thread-sphere test; if wave has dirty threads: 4 bucket
//    ballots build a wave-private list; rounds process 32 buckets/round
//    (2 lanes/bucket, 4 pts/lane, ds_read_b128/ds_write_b128); pair-DPP
//    reduce -> s_bkey; owners re-read dirty keys, update thresholds, wave
//    DPP max -> cand slot. Clean waves just re-contribute cached wmax.
//
//    Key = (d_bits<<26) | (8191-pid)<<13 | pos : u64 max == (max d, then min
//    ORIGINAL index) == jnp.argmax first-occurrence. Skip proof (bucket): if
//    dist(win,c) > sqrt(bd*1.0001)+rad then for all pts dist(win,pt) >=
//    dist-rad > sqrt(bd) >= sqrt(d[k]) -> fmin no-op, key unchanged. Same
//    inequality at thread level with (cT, radT, max bucket bd). Margins
//    (1.0001, 1.00002, +1e-12) dwarf ulps; identical arithmetic to the
//    previously-passing kernels. Updates are exact fmin -> order-free.
// ---------------------------------------------------------------------------
__global__ __launch_bounds__(256, 1) void fps_kernel(const float* __restrict__ xyz,
                                                     float* __restrict__ new_xyz) {
  const int b = blockIdx.x;
  const int t = threadIdx.x;    // 0..255
  const int lane = t & 63;
  const int w = t >> 6;         // 0..3
  const float* xb = xyz + (size_t)b * N_ * 3;

  __shared__ __align__(16) float s_px[N_];          // 32 KiB sorted x
  __shared__ __align__(16) float s_py[N_];          // 32 KiB sorted y
  __shared__ __align__(16) float s_pz[N_];          // 32 KiB sorted z
  __shared__ __align__(16) float s_d[N_];           // 32 KiB min dists (sort scratch union)
  __shared__ __align__(16) unsigned short s_pid[N_];// 16 KiB original ids
  __shared__ unsigned long long s_bkey[N_ / 8];     //  8 KiB per-bucket argmax key
  __shared__ int s_wlist[4][256];                   //  4 KiB per-wave dirty lists
  __shared__ unsigned long long s_cand[2][4];       // parity-buffered wave candidates

  int* hist = (int*)s_d;        // sort scratch aliases s_d (dead until init)
  int* boff = hist + 512;
  int* wsum = boff + 512;

  // ---- counting sort by morton cell (SoA + u16 pid) ----
  hist[t] = 0; hist[t + 256] = 0;
  __syncthreads();
#pragma unroll 4
  for (int rr = 0; rr < 32; ++rr) {
    int i = rr * 256 + t;
    float X = xb[i * 3 + 0], Y = xb[i * 3 + 1], Z = xb[i * 3 + 2];
    int ix = min(7, max(0, (int)(X * 8.0f)));
    int iy = min(7, max(0, (int)(Y * 8.0f)));
    int iz = min(7, max(0, (int)(Z * 8.0f)));
    atomicAdd(&hist[morton8(ix, iy, iz)], 1);
  }
  __syncthreads();
  // exclusive scan of 512 bins: thread t owns bins 2t, 2t+1
  {
    int v0 = hist[2 * t], v1 = hist[2 * t + 1];
    int sp = v0 + v1, v = sp;
#pragma unroll
    for (int off = 1; off < 64; off <<= 1) {
      int n = __shfl_up(v, off);
      if (lane >= off) v += n;
    }
    if (lane == 63) wsum[w] = v;
    __syncthreads();
    if (t == 0) {
      int acc = 0;
#pragma unroll
      for (int j = 0; j < 4; ++j) { int x0 = wsum[j]; wsum[j] = acc; acc += x0; }
    }
    __syncthreads();
    int base = v - sp + wsum[w];
    boff[2 * t] = base;
    boff[2 * t + 1] = base + v0;
  }
  __syncthreads();
#pragma unroll 4
  for (int rr = 0; rr < 32; ++rr) {
    int i = rr * 256 + t;
    float X = xb[i * 3 + 0], Y = xb[i * 3 + 1], Z = xb[i * 3 + 2];
    int ix = min(7, max(0, (int)(X * 8.0f)));
    int iy = min(7, max(0, (int)(Y * 8.0f)));
    int iz = min(7, max(0, (int)(Z * 8.0f)));
    int pos = atomicAdd(&boff[morton8(ix, iy, iz)], 1);
    s_px[pos] = X; s_py[pos] = Y; s_pz[pos] = Z;
    s_pid[pos] = (unsigned short)i;
  }
  __syncthreads();  // sort done; hist/boff scratch (in s_d) dead below

  // ---- per-thread init: 4 buckets (centroid, rad, key) + thread sphere ----
  float csx[4], csy[4], csz[4], rads[4], thrs[4];
  unsigned long long ks[4];
  float cTx = 0.f, cTy = 0.f, cTz = 0.f;
#pragma unroll
  for (int s = 0; s < 4; ++s) {
    int base = t * 32 + s * 8;
    float sx = 0.f, sy = 0.f, sz = 0.f;
#pragma unroll
    for (int j = 0; j < 8; ++j) { sx += s_px[base + j]; sy += s_py[base + j]; sz += s_pz[base + j]; }
    csx[s] = sx * 0.125f; csy[s] = sy * 0.125f; csz[s] = sz * 0.125f;
    cTx += sx; cTy += sy; cTz += sz;
  }
  cTx *= (1.f / 32.f); cTy *= (1.f / 32.f); cTz *= (1.f / 32.f);
  float r2T = 0.f;
#pragma unroll
  for (int s = 0; s < 4; ++s) {
    int base = t * 32 + s * 8;
    float r2 = 0.f; unsigned mlk = 0;
#pragma unroll
    for (int j = 0; j < 8; ++j) {
      int p2 = base + j;
      float X = s_px[p2], Y = s_py[p2], Z = s_pz[p2];
      float dx = X - csx[s], dy = Y - csy[s], dz = Z - csz[s];
      r2 = fmaxf(r2, dx * dx + dy * dy + dz * dz);
      float tx = X - cTx, ty = Y - cTy, tz = Z - cTz;
      r2T = fmaxf(r2T, tx * tx + ty * ty + tz * tz);
      unsigned pid = s_pid[p2];
      unsigned lk = ((8191u - pid) << 13) | (unsigned)p2;
      mlk = lk > mlk ? lk : mlk;
      s_d[p2] = 1e10f;  // == f32(10000000000.0), matches jnp init exactly
    }
    rads[s] = sqrtf(r2) * 1.00002f + 1e-12f;
    ks[s] = ((unsigned long long)(unsigned)__float_as_int(1e10f) << 26) | mlk;
    thrs[s] = 3e38f;  // never skip until first update
    s_bkey[4 * t + s] = ks[s];
  }
  const float radT = sqrtf(r2T) * 1.00002f + 1e-12f;
  float thrT = 3e38f;

  unsigned long long tmax = ks[0];
  if (ks[1] > tmax) tmax = ks[1];
  if (ks[2] > tmax) tmax = ks[2];
  if (ks[3] > tmax) tmax = ks[3];
  unsigned long long wmax = wave_max_u64_dpp(tmax);  // valid at lane 63
  if (lane == 63) s_cand[0][w] = wmax;

  float* dst = new_xyz + (size_t)b * M_ * 3;

  for (int it = 0; it < M_; ++it) {
    __syncthreads();  // ONLY barrier this iteration
    const int p = it & 1;
    unsigned long long ck = s_cand[p][lane & 3];  // 16-way bcast ds_read_b64
#define Q_STEP(ctrl)                                                           \
    {                                                                          \
      int klo = (int)(unsigned)ck, khi = (int)(unsigned)(ck >> 32);            \
      int olo = __builtin_amdgcn_update_dpp(klo, klo, ctrl, 0xf, 0xf, false);  \
      int ohi = __builtin_amdgcn_update_dpp(khi, khi, ctrl, 0xf, 0xf, false);  \
      unsigned long long ok =                                                  \
          ((unsigned long long)(unsigned)ohi << 32) | (unsigned)olo;           \
      if (ok > ck) ck = ok;                                                    \
    }
    Q_STEP(0xB1)  // quad_perm [1,0,3,2]
    Q_STEP(0x4E)  // quad_perm [2,3,0,1]
#undef Q_STEP
    const int winPos = (int)(unsigned)ck & 8191;
    const float lx = s_px[winPos], ly = s_py[winPos], lz = s_pz[winPos];
    if (t == 0) {  // fire-and-forget winner store, off the critical path
      dst[it * 3 + 0] = lx; dst[it * 3 + 1] = ly; dst[it * 3 + 2] = lz;
    }

    // ---- thread-sphere skip test ----
    float ex = lx - cTx, ey = ly - cTy, ez = lz - cTz;
    float dc2T = ex * ex + ey * ey + ez * ez;
    bool dirtyT = dc2T <= thrT;
    if (__ballot(dirtyT) != 0ull) {
      bool dB0 = false, dB1 = false, dB2 = false, dB3 = false;
      int cnt = 0;
#define BTEST(s, dBs)                                                          \
      {                                                                        \
        bool db = false;                                                       \
        if (dirtyT) {                                                          \
          float bx_ = lx - csx[s], by_ = ly - csy[s], bz_ = lz - csz[s];       \
          db = (bx_ * bx_ + by_ * by_ + bz_ * bz_) <= thrs[s];                 \
        }                                                                      \
        unsigned long long ms = __ballot(db);                                  \
        if (db) {                                                              \
          int pn = cnt + __popcll(ms & ((1ull << lane) - 1ull));               \
          s_wlist[w][pn] = 4 * t + (s);                                        \
        }                                                                      \
        cnt += __popcll(ms);                                                   \
        dBs = db;                                                              \
      }
      BTEST(0, dB0) BTEST(1, dB1) BTEST(2, dB2) BTEST(3, dB3)
#undef BTEST
      if (cnt > 0) {  // wave-uniform
        asm volatile("s_waitcnt lgkmcnt(0)" ::: "memory");
        int rounds = (cnt + 31) >> 5;  // 32 buckets/round, 2 lanes/bucket
        for (int r = 0; r < rounds; ++r) {
          int gi = r * 32 + (lane >> 1);
          bool act = gi < cnt;
          int bkt = s_wlist[w][act ? gi : 0];
          int pb = bkt * 8 + (lane & 1) * 4;
          float4 X4 = *(const float4*)&s_px[pb];
          float4 Y4 = *(const float4*)&s_py[pb];
          float4 Z4 = *(const float4*)&s_pz[pb];
          float4 D4 = *(float4*)&s_d[pb];
          ushort4 P4 = *(const ushort4*)&s_pid[pb];
          unsigned long long bk = 0ull;
#define UPD(Xc, Yc, Zc, Dc, Pc, off)                                           \
          {                                                                    \
            float dist = sqdist_rn(Xc, Yc, Zc, lx, ly, lz);                    \
            float dm = fminf(Dc, dist); /* exact min: order-free, skip-safe */ \
            Dc = dm;                                                           \
            unsigned long long key =                                           \
                ((unsigned long long)(unsigned)__float_as_int(dm) << 26) |     \
                (((8191u - (unsigned)(Pc)) << 13) | (unsigned)(pb + (off)));   \
            if (key > bk) bk = key;                                            \
          }
          UPD(X4.x, Y4.x, Z4.x, D4.x, P4.x, 0)
          UPD(X4.y, Y4.y, Z4.y, D4.y, P4.y, 1)
          UPD(X4.z, Y4.z, Z4.z, D4.z, P4.z, 2)
          UPD(X4.w, Y4.w, Z4.w, D4.w, P4.w, 3)
#undef UPD
          if (act) *(float4*)&s_d[pb] = D4;
          // pair reduce (lanes 2i <-> 2i+1), all-VALU
          {
            int klo = (int)(unsigned)bk, khi = (int)(unsigned)(bk >> 32);
            int olo = __builtin_amdgcn_update_dpp(klo, klo, 0xB1, 0xf, 0xf, false);
            int ohi = __builtin_amdgcn_update_dpp(khi, khi, 0xB1, 0xf, 0xf, false);
            unsigned long long ok =
                ((unsigned long long)(unsigned)ohi << 32) | (unsigned)olo;
            if (ok > bk) bk = ok;
          }
          if (act && !(lane & 1)) s_bkey[bkt] = bk;
        }
        asm volatile("s_waitcnt lgkmcnt(0)" ::: "memory");
        // owners re-read dirty keys, tighten thresholds
#define RDB(s, dBs)                                                            \
        if (dBs) {                                                             \
          ks[s] = s_bkey[4 * t + (s)];                                         \
          float bd = __int_as_float((int)(unsigned)(ks[s] >> 26));             \
          float sr = sqrtf(bd * 1.0001f) + rads[s];                            \
          thrs[s] = sr * sr;                                                   \
        }
        RDB(0, dB0) RDB(1, dB1) RDB(2, dB2) RDB(3, dB3)
#undef RDB
        tmax = ks[0];
        if (ks[1] > tmax) tmax = ks[1];
        if (ks[2] > tmax) tmax = ks[2];
        if (ks[3] > tmax) tmax = ks[3];
        if (dB0 | dB1 | dB2 | dB3) {
          float bdT = __int_as_float((int)(unsigned)(tmax >> 26));
          float srT = sqrtf(bdT * 1.0001f) + radT;
          thrT = srT * srT;
        }
        wmax = wave_max_u64_dpp(tmax);
      }
    }
    if (lane == 63) s_cand[p ^ 1][w] = wmax;  // plain b64 write, no atomic
  }
}

// ---------------------------------------------------------------------------
// 2) Fused ball-query + grouping + MLP(67->128 relu ->256) + max over K.
//    One block (256 thr) per centroid. Ball query: wave w scans index chunk
//    [w*2048,(w+1)*2048) in order, ballot-appends first <=32 valid to its own
//    LDS list; lists concat in wave order == global index order (pointnet2
//    first-K semantics). Writes pre-BN pooled features TRANSPOSED into the
//    final (B,C2,M) output region (no scratch needed).
// ---------------------------------------------------------------------------
__global__ __launch_bounds__(256) void mlp_kernel(const float* __restrict__ xyz,
                                                  const float* __restrict__ x,
                                                  const float* __restrict__ W1,
                                                  const float* __restrict__ b1,
                                                  const float* __restrict__ W2,
                                                  const float* __restrict__ b2,
                                                  const float* __restrict__ new_xyz,
                                                  float* __restrict__ outp) {
  __shared__ float sGRed[32 * 69];   // group tile; unioned w/ 8x256 max-red
  __shared__ float sU[128 * 69];     // W1 staged; unioned w/ 32x256 W2 tile
  __shared__ float sH1[32 * 132];
  __shared__ int sWIdx[4][K_];
  __shared__ int sWCnt[4];
  __shared__ int sIdx[K_];
  __shared__ float sQ[3];

  const int gm = blockIdx.x;
  const int b = gm >> 11;    // M_ = 2048
  const int m = gm & 2047;
  const int t = threadIdx.x;
  const int lane = t & 63;
  const int w = t >> 6;
  const float* xb = xyz + (size_t)b * N_ * 3;

  if (t < 3) sQ[t] = new_xyz[(size_t)gm * 3 + t];
  __syncthreads();
  const float qx = sQ[0], qy = sQ[1], qz = sQ[2];
  // (float)(0.1*0.1) = 0x3C23D70A; 0.1f*0.1f rounds differently — wrong.
  const float R2 = (float)(0.1 * 0.1);

  // ---- ball query ----
  {
    int cnt = 0;
    const int cbeg = w * 2048, cend = cbeg + 2048;
    for (int base = cbeg; base < cend; base += 64) {
      int p = base + lane;
      float d2 = sqdist_rn(qx, qy, qz, xb[p * 3 + 0], xb[p * 3 + 1], xb[p * 3 + 2]);
      bool valid = d2 < R2;
      unsigned long long mask = __ballot(valid);
      if (valid) {
        int pos = cnt + __popcll(mask & ((1ull << lane) - 1ull));
        if (pos < K_) sWIdx[w][pos] = p;
      }
      cnt += __popcll(mask);
      if (cnt >= K_) break;  // wave-uniform
    }
    if (lane == 0) sWCnt[w] = (cnt < K_) ? cnt : K_;
  }
  __syncthreads();
  if (t < K_) {
    int c0 = sWCnt[0], c1 = sWCnt[1], c2 = sWCnt[2], c3 = sWCnt[3];
    int s1 = c0 + c1, s2 = s1 + c2, s3 = s2 + c3;
    int j = t, idx;
    if (j < c0) idx = sWIdx[0][j];
    else if (j < s1) idx = sWIdx[1][j - c0];
    else if (j < s2) idx = sWIdx[2][j - s1];
    else if (j < s3) idx = sWIdx[3][j - s2];
    else {
      int fw = c0 ? 0 : (c1 ? 1 : (c2 ? 2 : 3));
      idx = (s3 > 0) ? sWIdx[fw][0] : 0;  // fill with first valid index
    }
    sIdx[j] = idx;
  }
  __syncthreads();

  // ---- grouping: rel coords + features into sGRed (32 x 69 padded) ----
  if (t < K_) {
    int id = sIdx[t];
    sGRed[t * 69 + 0] = xb[id * 3 + 0] - qx;
    sGRed[t * 69 + 1] = xb[id * 3 + 1] - qy;
    sGRed[t * 69 + 2] = xb[id * 3 + 2] - qz;
  }
  {
    int r = t & 31;
    int c0 = (t >> 5) * 8;
    int id = sIdx[r];
    const float* xf = x + ((size_t)b * C0_ + c0) * N_ + id;
#pragma unroll
    for (int j = 0; j < 8; ++j) sGRed[r * 69 + 3 + c0 + j] = xf[(size_t)j * N_];
  }
  for (int i = t; i < C1_ * CIN_; i += 256) {
    sU[(i / CIN_) * 69 + (i % CIN_)] = W1[i];
  }
  __syncthreads();

  const int ol = t & 31;  // output-lane: o = ol + 32*j
  const int rg = t >> 5;  // row group: rows rg*4 .. rg*4+3

  // ---- layer 1: h1 = relu(G @ W1^T + b1), 4 rows x 4 outs per thread ----
  float acc[4][4] = {{0.f}};
  for (int c = 0; c < CIN_; ++c) {
    float g[4], wv[4];
#pragma unroll
    for (int i = 0; i < 4; ++i) g[i] = sGRed[(rg * 4 + i) * 69 + c];
#pragma unroll
    for (int j = 0; j < 4; ++j) wv[j] = sU[(ol + 32 * j) * 69 + c];
#pragma unroll
    for (int i = 0; i < 4; ++i)
#pragma unroll
      for (int j = 0; j < 4; ++j) acc[i][j] += g[i] * wv[j];
  }
#pragma unroll
  for (int j = 0; j < 4; ++j) {
    float bias = b1[ol + 32 * j];
#pragma unroll
    for (int i = 0; i < 4; ++i) {
      float v = acc[i][j] + bias;
      sH1[(rg * 4 + i) * 132 + ol + 32 * j] = fmaxf(v, 0.0f);
    }
  }

  // ---- layer 2: h2 = h1 @ W2^T, 4 rows x 8 outs per thread ----
  float acc2[4][8] = {{0.f}};
  for (int ct = 0; ct < 4; ++ct) {
    __syncthreads();  // sU reuse safe; (ct==0) also covers sH1 writes
    const float4* w4 = (const float4*)(W2 + (size_t)t * C1_ + ct * 32);
#pragma unroll
    for (int jj = 0; jj < 8; ++jj) {
      float4 v = w4[jj];
      sU[(jj * 4 + 0) * 256 + t] = v.x;
      sU[(jj * 4 + 1) * 256 + t] = v.y;
      sU[(jj * 4 + 2) * 256 + t] = v.z;
      sU[(jj * 4 + 3) * 256 + t] = v.w;
    }
    __syncthreads();
    for (int cc = 0; cc < 32; ++cc) {
      float h[4], wv[8];
#pragma unroll
      for (int i = 0; i < 4; ++i) h[i] = sH1[(rg * 4 + i) * 132 + ct * 32 + cc];
#pragma unroll
      for (int j = 0; j < 8; ++j) wv[j] = sU[cc * 256 + ol + 32 * j];
#pragma unroll
      for (int i = 0; i < 4; ++i)
#pragma unroll
        for (int j = 0; j < 8; ++j) acc2[i][j] += h[i] * wv[j];
    }
  }

  // ---- max over K, + b2 (max(x)+c == max(x+c): RN is monotone) ----
  __syncthreads();  // group tile dead; reuse sGRed as reduction buffer
#pragma unroll
  for (int j = 0; j < 8; ++j) {
    float pm = acc2[0][j];
#pragma unroll
    for (int i = 1; i < 4; ++i) pm = fmaxf(pm, acc2[i][j]);
    sGRed[rg * 256 + ol + 32 * j] = pm;
  }
  __syncthreads();
  {
    int o = t;
    float v = sGRed[o];
#pragma unroll
    for (int g = 1; g < 8; ++g) v = fmaxf(v, sGRed[g * 256 + o]);
    v += b2[o];
    // transposed store into final (B, C2, M) layout (pre-BN)
    outp[((size_t)(b * C2_ + o)) * M_ + m] = v;
  }
}

// ---------------------------------------------------------------------------
// 3) BN stats per channel (deterministic, double accum). One block / channel.
// ---------------------------------------------------------------------------
__global__ __launch_bounds__(256) void bn_stats_kernel(const float* __restrict__ outp,
                                                       const float* __restrict__ gamma,
                                                       float* __restrict__ stats) {
  const int o = blockIdx.x;
  const int t = threadIdx.x;
  double s = 0.0, s2 = 0.0;
  for (int b = 0; b < B_; ++b) {
    const float* p = outp + ((size_t)(b * C2_ + o)) * M_;
    for (int i = t; i < M_; i += 256) {
      float v = p[i];
      s += (double)v;
      s2 += (double)v * (double)v;
    }
  }
#pragma unroll
  for (int off = 32; off > 0; off >>= 1) {
    s += __shfl_xor(s, off);
    s2 += __shfl_xor(s2, off);
  }
  __shared__ double aS[4], aS2[4];
  if ((t & 63) == 0) { aS[t >> 6] = s; aS2[t >> 6] = s2; }
  __syncthreads();
  if (t == 0) {
    double S = aS[0] + aS[1] + aS[2] + aS[3];
    double S2 = aS2[0] + aS2[1] + aS2[2] + aS2[3];
    double mean = S / (double)(B_ * M_);
    double var = S2 / (double)(B_ * M_) - mean * mean;
    float rstd = 1.0f / sqrtf((float)var + 1e-5f);
    stats[o] = (float)mean;
    stats[C2_ + o] = gamma[o] * rstd;
  }
}

// ---------------------------------------------------------------------------
// 4) BN apply, in place on the (B,C2,M) output region. float4-vectorized.
// ---------------------------------------------------------------------------
__global__ __launch_bounds__(256) void bn_apply_kernel(float* __restrict__ outp,
                                                       const float* __restrict__ stats,
                                                       const float* __restrict__ beta) {
  const int i4 = blockIdx.x * 256 + threadIdx.x;  // B_*C2_*M_/4 = 262144
  const int ch = (i4 >> 9) & 255;                 // M_/4 = 512 float4 / chan
  const float mean = stats[ch];
  const float scale = stats[C2_ + ch];
  const float bt = beta[ch];
  float4 v = ((const float4*)outp)[i4];
  v.x = (v.x - mean) * scale + bt;
  v.y = (v.y - mean) * scale + bt;
  v.z = (v.z - mean) * scale + bt;
  v.w = (v.w - mean) * scale + bt;
  ((float4*)outp)[i4] = v;
}

// ---------------------------------------------------------------------------
extern "C" void kernel_launch(void* const* d_in, const int* in_sizes, int n_in,
                              void* d_out, int out_size, void* d_ws, size_t ws_size,
                              hipStream_t stream) {
  const float* xyz   = (const float*)d_in[0];
  const float* x     = (const float*)d_in[1];
  const float* W1    = (const float*)d_in[2];
  const float* b1    = (const float*)d_in[3];
  const float* W2    = (const float*)d_in[4];
  const float* b2    = (const float*)d_in[5];
  const float* gamma = (const float*)d_in[6];
  const float* beta  = (const float*)d_in[7];

  float* new_xyz = (float*)d_out;                       // (B, M, 3)
  float* outp    = (float*)d_out + (size_t)B_ * M_ * 3; // (B, C2, M)
  float* stats   = (float*)d_ws;                        // 2*C2 floats = 2 KB

  fps_kernel<<<B_, 256, 0, stream>>>(xyz, new_xyz);
  mlp_kernel<<<B_ * M_, 256, 0, stream>>>(xyz, x, W1, b1, W2, b2, new_xyz, outp);
  bn_stats_kernel<<<C2_, 256, 0, stream>>>(outp, gamma, stats);
  bn_apply_kernel<<<(B_ * C2_ * M_ / 4) / 256, 256, 0, stream>>>(outp, stats, beta);
}

// Round 4
// 2677.795 us; speedup vs baseline: 1.3055x; 1.3055x over previous
//
#include <hip/hip_runtime.h>
#include <cstdint>
#include <cstddef>

#define B_   2
#define N_   8192
#define M_   2048
#define K_   32
#define C0_  64
#define C1_  128
#define C2_  256
#define CIN_ 67

// Exact-match distance: reference computes sum((a-b)**2, axis=-1) in f32 as
// ((dx^2 + dy^2) + dz^2) with no FMA contraction. _rn intrinsics forbid
// contract-fast fma fusion (would flip argmax / radius-boundary decisions).
__device__ __forceinline__ float sqdist_rn(float ax, float ay, float az,
                                           float bx, float by, float bz) {
  float dx = __fsub_rn(ax, bx);
  float dy = __fsub_rn(ay, by);
  float dz = __fsub_rn(az, bz);
  return __fadd_rn(__fadd_rn(__fmul_rn(dx, dx), __fmul_rn(dy, dy)),
                   __fmul_rn(dz, dz));
}

__device__ __forceinline__ int morton8(int ix, int iy, int iz) {
  int m = 0;
#pragma unroll
  for (int b = 0; b < 3; ++b) {
    m |= (((ix >> b) & 1) << (3 * b + 2)) | (((iy >> b) & 1) << (3 * b + 1)) |
         (((iz >> b) & 1) << (3 * b + 0));
  }
  return m;
}

// u64 max across the wave via paired DPP (row_shr 1/2/4/8, row_bcast 15/31);
// cumulative max lands in lane 63. bound_ctrl=false + old=self => lanes with
// no source contribute their own value (max(v,v)=v). Exact tie-break is baked
// into the key (d | inv_pid | pos), so a plain unsigned max is sufficient.
__device__ __forceinline__ unsigned long long wave_max_u64_dpp(unsigned long long k) {
#define FPS_STEP(ctrl)                                                         \
  {                                                                            \
    int klo = (int)(unsigned)k, khi = (int)(unsigned)(k >> 32);                \
    int olo = __builtin_amdgcn_update_dpp(klo, klo, ctrl, 0xf, 0xf, false);    \
    int ohi = __builtin_amdgcn_update_dpp(khi, khi, ctrl, 0xf, 0xf, false);    \
    unsigned long long ok =                                                    \
        ((unsigned long long)(unsigned)ohi << 32) | (unsigned)olo;             \
    if (ok > k) k = ok;                                                        \
  }
  FPS_STEP(0x111)  // row_shr:1
  FPS_STEP(0x112)  // row_shr:2
  FPS_STEP(0x114)  // row_shr:4
  FPS_STEP(0x118)  // row_shr:8
  FPS_STEP(0x142)  // row_bcast:15
  FPS_STEP(0x143)  // row_bcast:31
#undef FPS_STEP
  return k;
}

// ---------------------------------------------------------------------------
// 1) Furthest point sampling — LDS-resident state + per-wave dirty-bucket
//    compaction with FAT rounds, ONE barrier per iteration, 16 waves.
//
//    Round-3 post-mortem: (a) global stores inside the loop are poison —
//    __syncthreads drains vmcnt(0), so winner parking stays in REGISTERS;
//    (b) 1 wave/SIMD exposes all LDS latency — stay at 16 waves (4/SIMD).
//    R3's residual cost: the one dirty wave serially ran ceil(D/8) thin
//    rounds (8 buckets/round, 5 scalar ds_read_b32 each) = 500-2000 cy while
//    15 waves idled at the barrier. This version processes 32 buckets/round
//    (2 lanes/bucket, 4 pts/lane) with ds_read_b128/ds_write_b128 + ushort4
//    and a pair-DPP (quad_perm xor1) bucket reduce: <=2 rounds ever, 1 round
//    at steady state. Everything else is byte-identical to the 2386 µs R3
//    kernel (atomic sWin + mod-3 rotating clear protocol, register parking,
//    exact arithmetic).
//
//    Key = (d_bits<<26) | (8191-pid)<<13 | pos : u64 max == (max d, then min
//    ORIGINAL index) == jnp.argmax first-occurrence. Skips are provably
//    no-ops: skip bucket iff dist(win, centroid) > sqrt(bd*1.0001)+rad, then
//    for every point dist(win,pt) >= dist-rad > sqrt(bd) >= sqrt(d[k]), so
//    fmin is a no-op and the bucket key cannot change (margins dwarf ulps).
//    Updates are exact fmin -> order-free.
// ---------------------------------------------------------------------------
__global__ __launch_bounds__(1024, 1) void fps_kernel(const float* __restrict__ xyz,
                                                      float* __restrict__ new_xyz) {
  const int b = blockIdx.x;
  const int t = threadIdx.x;
  const int lane = t & 63;
  const int w = t >> 6;
  const float* xb = xyz + (size_t)b * N_ * 3;

  __shared__ __align__(16) float s_px[N_];          // 32 KiB sorted x
  __shared__ __align__(16) float s_py[N_];          // 32 KiB sorted y
  __shared__ __align__(16) float s_pz[N_];          // 32 KiB sorted z
  __shared__ __align__(16) float s_d[N_];           // 32 KiB min dists (sort scratch union)
  __shared__ __align__(16) unsigned short s_pid[N_];// 16 KiB original ids
  __shared__ unsigned long long s_bkey[N_ / 8];     //  8 KiB per-bucket argmax key
  __shared__ int s_wlist[16][64];                   //  4 KiB per-wave dirty lists
  __shared__ unsigned long long sWin[3];            // rotating winner slots

  int* hist = (int*)s_d;        // sort scratch aliases s_d (dead until init)
  int* boff = hist + 512;
  int* wsum = boff + 512;

  // ---- counting sort by morton cell (SoA + u16 pid) ----
  if (t < 512) hist[t] = 0;
  if (t < 3) sWin[t] = 0ull;
  __syncthreads();
#pragma unroll
  for (int rr = 0; rr < 8; ++rr) {
    int i = rr * 1024 + t;
    float X = xb[i * 3 + 0], Y = xb[i * 3 + 1], Z = xb[i * 3 + 2];
    int ix = min(7, max(0, (int)(X * 8.0f)));
    int iy = min(7, max(0, (int)(Y * 8.0f)));
    int iz = min(7, max(0, (int)(Z * 8.0f)));
    atomicAdd(&hist[morton8(ix, iy, iz)], 1);
  }
  __syncthreads();
  // exclusive scan of 512 bins (8 active waves)
  {
    int ov = (t < 512) ? hist[t] : 0;
    int v = ov;
#pragma unroll
    for (int off = 1; off < 64; off <<= 1) {
      int n = __shfl_up(v, off);
      if (lane >= off) v += n;
    }
    if (t < 512 && lane == 63) wsum[w] = v;
    __syncthreads();
    if (t == 0) {
      int acc = 0;
#pragma unroll
      for (int j = 0; j < 8; ++j) { int x0 = wsum[j]; wsum[j] = acc; acc += x0; }
    }
    __syncthreads();
    if (t < 512) boff[t] = v - ov + wsum[w];
  }
  __syncthreads();
#pragma unroll
  for (int rr = 0; rr < 8; ++rr) {
    int i = rr * 1024 + t;
    float X = xb[i * 3 + 0], Y = xb[i * 3 + 1], Z = xb[i * 3 + 2];
    int ix = min(7, max(0, (int)(X * 8.0f)));
    int iy = min(7, max(0, (int)(Y * 8.0f)));
    int iz = min(7, max(0, (int)(Z * 8.0f)));
    int pos = atomicAdd(&boff[morton8(ix, iy, iz)], 1);
    s_px[pos] = X; s_py[pos] = Y; s_pz[pos] = Z;
    s_pid[pos] = (unsigned short)i;
  }
  __syncthreads();  // sort done; s_d scratch dead -> init below may overwrite

  // ---- per-bucket init: meta in registers, d + bkey in LDS ----
  float cx = 0.f, cy = 0.f, cz = 0.f;
  unsigned maxlowk = 0;
  {
    float sx = 0.f, sy = 0.f, sz = 0.f;
#pragma unroll
    for (int k = 0; k < 8; ++k) {
      int p = 8 * t + k;
      sx += s_px[p]; sy += s_py[p]; sz += s_pz[p];
      unsigned pid = s_pid[p];
      unsigned lk = ((8191u - pid) << 13) | (unsigned)p;
      maxlowk = lk > maxlowk ? lk : maxlowk;
      s_d[p] = 1e10f;  // == f32(10000000000.0), matches jnp init exactly
    }
    cx = sx * 0.125f; cy = sy * 0.125f; cz = sz * 0.125f;
  }
  float r2m = 0.f;
#pragma unroll
  for (int k = 0; k < 8; ++k) {
    int p = 8 * t + k;
    float dx = s_px[p] - cx, dy = s_py[p] - cy, dz = s_pz[p] - cz;
    r2m = fmaxf(r2m, dx * dx + dy * dy + dz * dz);
  }
  const float rad = sqrtf(r2m) * 1.00002f + 1e-12f;
  unsigned long long kinit =
      ((unsigned long long)(unsigned)__float_as_int(1e10f) << 26) | maxlowk;
  s_bkey[t] = kinit;
  unsigned long long wmax = wave_max_u64_dpp(kinit);  // valid at lane 63
  float thrT = 3e38f;  // never skip until first update sets it

  // per-thread winner parking: thread t owns output rows m=t and m=t+1024
  float wx0 = 0.f, wy0 = 0.f, wz0 = 0.f, wx1 = 0.f, wy1 = 0.f, wz1 = 0.f;

  int u = 0;
  for (int it = 0; it < M_; ++it) {
    if (lane == 63) atomicMax(&sWin[u], wmax);
    int nu = (u == 2) ? 0 : u + 1;
    if (t == 0) sWin[nu] = 0ull;  // clear slot used next iter (mod-3 protocol)
    __syncthreads();              // ONLY barrier this iteration

    unsigned long long wk = sWin[u];          // broadcast ds_read_b64
    u = nu;
    int winPos = (int)(unsigned)wk & 8191;
    float lx = s_px[winPos], ly = s_py[winPos], lz = s_pz[winPos];
    if (it == t)        { wx0 = lx; wy0 = ly; wz0 = lz; }
    if (it == 1024 + t) { wx1 = lx; wy1 = ly; wz1 = lz; }

    // ---- conservative per-bucket skip test (register meta) ----
    float ex = lx - cx, ey = ly - cy, ez = lz - cz;
    float dc2 = ex * ex + ey * ey + ez * ez;
    bool dirty = dc2 <= thrT;
    unsigned long long mask = __ballot(dirty);
    if (mask != 0ull) {  // wave has work; clean waves skip to next iter
      int Dw = __popcll(mask);
      if (dirty) {
        int pre = __popcll(mask & ((1ull << lane) - 1ull));
        s_wlist[w][pre] = t;  // wave-private list; in-wave DS ordering
      }
      asm volatile("s_waitcnt lgkmcnt(0)" ::: "memory");
      // FAT rounds: 32 buckets/round, 2 lanes/bucket, 4 pts/lane, b128 LDS.
      int rounds = (Dw + 31) >> 5;
      for (int r = 0; r < rounds; ++r) {
        int gi = r * 32 + (lane >> 1);
        bool act = gi < Dw;
        int bkt = s_wlist[w][act ? gi : 0];
        int pb = bkt * 8 + (lane & 1) * 4;
        float4 X4 = *(const float4*)&s_px[pb];
        float4 Y4 = *(const float4*)&s_py[pb];
        float4 Z4 = *(const float4*)&s_pz[pb];
        float4 D4 = *(float4*)&s_d[pb];
        ushort4 P4 = *(const ushort4*)&s_pid[pb];
        unsigned long long bk = 0ull;
#define UPD(Xc, Yc, Zc, Dc, Pc, off)                                           \
        {                                                                      \
          float dist = sqdist_rn(Xc, Yc, Zc, lx, ly, lz);                      \
          float dm = fminf(Dc, dist); /* exact min: order-free, skip-safe */   \
          Dc = dm;                                                             \
          unsigned long long key =                                             \
              ((unsigned long long)(unsigned)__float_as_int(dm) << 26) |       \
              (((8191u - (unsigned)(Pc)) << 13) | (unsigned)(pb + (off)));     \
          if (key > bk) bk = key;                                              \
        }
        UPD(X4.x, Y4.x, Z4.x, D4.x, P4.x, 0)
        UPD(X4.y, Y4.y, Z4.y, D4.y, P4.y, 1)
        UPD(X4.z, Y4.z, Z4.z, D4.z, P4.z, 2)
        UPD(X4.w, Y4.w, Z4.w, D4.w, P4.w, 3)
#undef UPD
        if (act) *(float4*)&s_d[pb] = D4;
        // pair reduce (lanes 2i <-> 2i+1), all-VALU (quad_perm xor1)
        {
          int klo = (int)(unsigned)bk, khi = (int)(unsigned)(bk >> 32);
          int olo = __builtin_amdgcn_update_dpp(klo, klo, 0xB1, 0xf, 0xf, false);
          int ohi = __builtin_amdgcn_update_dpp(khi, khi, 0xB1, 0xf, 0xf, false);
          unsigned long long ok =
              ((unsigned long long)(unsigned)ohi << 32) | (unsigned)olo;
          if (ok > bk) bk = ok;
        }
        if (act && !(lane & 1)) s_bkey[bkt] = bk;
      }
      asm volatile("s_waitcnt lgkmcnt(0)" ::: "memory");
      unsigned long long nk = s_bkey[t];  // own bucket (maybe just updated)
      if (dirty) {
        float bd = __int_as_float((int)(unsigned)(nk >> 26));
        float sr = sqrtf(bd * 1.0001f) + rad;  // conservative: margins dwarf ulp
        thrT = sr * sr;
      }
      wmax = wave_max_u64_dpp(nk);  // recompute wave max over all 64 buckets
    }
  }

  // ---- dump winners straight from registers (dense across the block) ----
  {
    float* dst = new_xyz + (size_t)b * M_ * 3;
    dst[t * 3 + 0] = wx0;
    dst[t * 3 + 1] = wy0;
    dst[t * 3 + 2] = wz0;
    dst[(1024 + t) * 3 + 0] = wx1;
    dst[(1024 + t) * 3 + 1] = wy1;
    dst[(1024 + t) * 3 + 2] = wz1;
  }
}

// ---------------------------------------------------------------------------
// 2) Fused ball-query + grouping + MLP(67->128 relu ->256) + max over K.
//    One block (256 thr) per centroid. Ball query: wave w scans index chunk
//    [w*2048,(w+1)*2048) in order, ballot-appends first <=32 valid to its own
//    LDS list; lists concat in wave order == global index order (pointnet2
//    first-K semantics). Writes pre-BN pooled features TRANSPOSED into the
//    final (B,C2,M) output region (no scratch needed).
// ---------------------------------------------------------------------------
__global__ __launch_bounds__(256) void mlp_kernel(const float* __restrict__ xyz,
                                                  const float* __restrict__ x,
                                                  const float* __restrict__ W1,
                                                  const float* __restrict__ b1,
                                                  const float* __restrict__ W2,
                                                  const float* __restrict__ b2,
                                                  const float* __restrict__ new_xyz,
                                                  float* __restrict__ outp) {
  __shared__ float sGRed[32 * 69];   // group tile; unioned w/ 8x256 max-red
  __shared__ float sU[128 * 69];     // W1 staged; unioned w/ 32x256 W2 tile
  __shared__ float sH1[32 * 132];
  __shared__ int sWIdx[4][K_];
  __shared__ int sWCnt[4];
  __shared__ int sIdx[K_];
  __shared__ float sQ[3];

  const int gm = blockIdx.x;
  const int b = gm >> 11;    // M_ = 2048
  const int m = gm & 2047;
  const int t = threadIdx.x;
  const int lane = t & 63;
  const int w = t >> 6;
  const float* xb = xyz + (size_t)b * N_ * 3;

  if (t < 3) sQ[t] = new_xyz[(size_t)gm * 3 + t];
  __syncthreads();
  const float qx = sQ[0], qy = sQ[1], qz = sQ[2];
  // (float)(0.1*0.1) = 0x3C23D70A; 0.1f*0.1f rounds differently — wrong.
  const float R2 = (float)(0.1 * 0.1);

  // ---- ball query ----
  {
    int cnt = 0;
    const int cbeg = w * 2048, cend = cbeg + 2048;
    for (int base = cbeg; base < cend; base += 64) {
      int p = base + lane;
      float d2 = sqdist_rn(qx, qy, qz, xb[p * 3 + 0], xb[p * 3 + 1], xb[p * 3 + 2]);
      bool valid = d2 < R2;
      unsigned long long mask = __ballot(valid);
      if (valid) {
        int pos = cnt + __popcll(mask & ((1ull << lane) - 1ull));
        if (pos < K_) sWIdx[w][pos] = p;
      }
      cnt += __popcll(mask);
      if (cnt >= K_) break;  // wave-uniform
    }
    if (lane == 0) sWCnt[w] = (cnt < K_) ? cnt : K_;
  }
  __syncthreads();
  if (t < K_) {
    int c0 = sWCnt[0], c1 = sWCnt[1], c2 = sWCnt[2], c3 = sWCnt[3];
    int s1 = c0 + c1, s2 = s1 + c2, s3 = s2 + c3;
    int j = t, idx;
    if (j < c0) idx = sWIdx[0][j];
    else if (j < s1) idx = sWIdx[1][j - c0];
    else if (j < s2) idx = sWIdx[2][j - s1];
    else if (j < s3) idx = sWIdx[3][j - s2];
    else {
      int fw = c0 ? 0 : (c1 ? 1 : (c2 ? 2 : 3));
      idx = (s3 > 0) ? sWIdx[fw][0] : 0;  // fill with first valid index
    }
    sIdx[j] = idx;
  }
  __syncthreads();

  // ---- grouping: rel coords + features into sGRed (32 x 69 padded) ----
  if (t < K_) {
    int id = sIdx[t];
    sGRed[t * 69 + 0] = xb[id * 3 + 0] - qx;
    sGRed[t * 69 + 1] = xb[id * 3 + 1] - qy;
    sGRed[t * 69 + 2] = xb[id * 3 + 2] - qz;
  }
  {
    int r = t & 31;
    int c0 = (t >> 5) * 8;
    int id = sIdx[r];
    const float* xf = x + ((size_t)b * C0_ + c0) * N_ + id;
#pragma unroll
    for (int j = 0; j < 8; ++j) sGRed[r * 69 + 3 + c0 + j] = xf[(size_t)j * N_];
  }
  for (int i = t; i < C1_ * CIN_; i += 256) {
    sU[(i / CIN_) * 69 + (i % CIN_)] = W1[i];
  }
  __syncthreads();

  const int ol = t & 31;  // output-lane: o = ol + 32*j
  const int rg = t >> 5;  // row group: rows rg*4 .. rg*4+3

  // ---- layer 1: h1 = relu(G @ W1^T + b1), 4 rows x 4 outs per thread ----
  float acc[4][4] = {{0.f}};
  for (int c = 0; c < CIN_; ++c) {
    float g[4], wv[4];
#pragma unroll
    for (int i = 0; i < 4; ++i) g[i] = sGRed[(rg * 4 + i) * 69 + c];
#pragma unroll
    for (int j = 0; j < 4; ++j) wv[j] = sU[(ol + 32 * j) * 69 + c];
#pragma unroll
    for (int i = 0; i < 4; ++i)
#pragma unroll
      for (int j = 0; j < 4; ++j) acc[i][j] += g[i] * wv[j];
  }
#pragma unroll
  for (int j = 0; j < 4; ++j) {
    float bias = b1[ol + 32 * j];
#pragma unroll
    for (int i = 0; i < 4; ++i) {
      float v = acc[i][j] + bias;
      sH1[(rg * 4 + i) * 132 + ol + 32 * j] = fmaxf(v, 0.0f);
    }
  }

  // ---- layer 2: h2 = h1 @ W2^T, 4 rows x 8 outs per thread ----
  float acc2[4][8] = {{0.f}};
  for (int ct = 0; ct < 4; ++ct) {
    __syncthreads();  // sU reuse safe; (ct==0) also covers sH1 writes
    const float4* w4 = (const float4*)(W2 + (size_t)t * C1_ + ct * 32);
#pragma unroll
    for (int jj = 0; jj < 8; ++jj) {
      float4 v = w4[jj];
      sU[(jj * 4 + 0) * 256 + t] = v.x;
      sU[(jj * 4 + 1) * 256 + t] = v.y;
      sU[(jj * 4 + 2) * 256 + t] = v.z;
      sU[(jj * 4 + 3) * 256 + t] = v.w;
    }
    __syncthreads();
    for (int cc = 0; cc < 32; ++cc) {
      float h[4], wv[8];
#pragma unroll
      for (int i = 0; i < 4; ++i) h[i] = sH1[(rg * 4 + i) * 132 + ct * 32 + cc];
#pragma unroll
      for (int j = 0; j < 8; ++j) wv[j] = sU[cc * 256 + ol + 32 * j];
#pragma unroll
      for (int i = 0; i < 4; ++i)
#pragma unroll
        for (int j = 0; j < 8; ++j) acc2[i][j] += h[i] * wv[j];
    }
  }

  // ---- max over K, + b2 (max(x)+c == max(x+c): RN is monotone) ----
  __syncthreads();  // group tile dead; reuse sGRed as reduction buffer
#pragma unroll
  for (int j = 0; j < 8; ++j) {
    float pm = acc2[0][j];
#pragma unroll
    for (int i = 1; i < 4; ++i) pm = fmaxf(pm, acc2[i][j]);
    sGRed[rg * 256 + ol + 32 * j] = pm;
  }
  __syncthreads();
  {
    int o = t;
    float v = sGRed[o];
#pragma unroll
    for (int g = 1; g < 8; ++g) v = fmaxf(v, sGRed[g * 256 + o]);
    v += b2[o];
    // transposed store into final (B, C2, M) layout (pre-BN)
    outp[((size_t)(b * C2_ + o)) * M_ + m] = v;
  }
}

// ---------------------------------------------------------------------------
// 3) BN stats per channel (deterministic, double accum). One block / channel.
// ---------------------------------------------------------------------------
__global__ __launch_bounds__(256) void bn_stats_kernel(const float* __restrict__ outp,
                                                       const float* __restrict__ gamma,
                                                       float* __restrict__ stats) {
  const int o = blockIdx.x;
  const int t = threadIdx.x;
  double s = 0.0, s2 = 0.0;
  for (int b = 0; b < B_; ++b) {
    const float* p = outp + ((size_t)(b * C2_ + o)) * M_;
    for (int i = t; i < M_; i += 256) {
      float v = p[i];
      s += (double)v;
      s2 += (double)v * (double)v;
    }
  }
#pragma unroll
  for (int off = 32; off > 0; off >>= 1) {
    s += __shfl_xor(s, off);
    s2 += __shfl_xor(s2, off);
  }
  __shared__ double aS[4], aS2[4];
  if ((t & 63) == 0) { aS[t >> 6] = s; aS2[t >> 6] = s2; }
  __syncthreads();
  if (t == 0) {
    double S = aS[0] + aS[1] + aS[2] + aS[3];
    double S2 = aS2[0] + aS2[1] + aS2[2] + aS2[3];
    double mean = S / (double)(B_ * M_);
    double var = S2 / (double)(B_ * M_) - mean * mean;
    float rstd = 1.0f / sqrtf((float)var + 1e-5f);
    stats[o] = (float)mean;
    stats[C2_ + o] = gamma[o] * rstd;
  }
}

// ---------------------------------------------------------------------------
// 4) BN apply, in place on the (B,C2,M) output region. float4-vectorized.
// ---------------------------------------------------------------------------
__global__ __launch_bounds__(256) void bn_apply_kernel(float* __restrict__ outp,
                                                       const float* __restrict__ stats,
                                                       const float* __restrict__ beta) {
  const int i4 = blockIdx.x * 256 + threadIdx.x;  // B_*C2_*M_/4 = 262144
  const int ch = (i4 >> 9) & 255;                 // M_/4 = 512 float4 / chan
  const float mean = stats[ch];
  const float scale = stats[C2_ + ch];
  const float bt = beta[ch];
  float4 v = ((const float4*)outp)[i4];
  v.x = (v.x - mean) * scale + bt;
  v.y = (v.y - mean) * scale + bt;
  v.z = (v.z - mean) * scale + bt;
  v.w = (v.w - mean) * scale + bt;
  ((float4*)outp)[i4] = v;
}

// ---------------------------------------------------------------------------
extern "C" void kernel_launch(void* const* d_in, const int* in_sizes, int n_in,
                              void* d_out, int out_size, void* d_ws, size_t ws_size,
                              hipStream_t stream) {
  const float* xyz   = (const float*)d_in[0];
  const float* x     = (const float*)d_in[1];
  const float* W1    = (const float*)d_in[2];
  const float* b1    = (const float*)d_in[3];
  const float* W2    = (const float*)d_in[4];
  const float* b2    = (const float*)d_in[5];
  const float* gamma = (const float*)d_in[6];
  const float* beta  = (const float*)d_in[7];

  float* new_xyz = (float*)d_out;                       // (B, M, 3)
  float* outp    = (float*)d_out + (size_t)B_ * M_ * 3; // (B, C2, M)
  float* stats   = (float*)d_ws;                        // 2*C2 floats = 2 KB

  fps_kernel<<<B_, 1024, 0, stream>>>(xyz, new_xyz);
  mlp_kernel<<<B_ * M_, 256, 0, stream>>>(xyz, x, W1, b1, W2, b2, new_xyz, outp);
  bn_stats_kernel<<<C2_, 256, 0, stream>>>(outp, gamma, stats);
  bn_apply_kernel<<<(B_ * C2_ * M_ / 4) / 256, 256, 0, stream>>>(outp, stats, beta);
}